// Round 14
// baseline (536.977 us; speedup 1.0000x reference)
//
#include <hip/hip_runtime.h>
#include <hip/hip_bf16.h>

typedef __attribute__((ext_vector_type(4))) float f32x4;
typedef __attribute__((ext_vector_type(8))) __bf16 bfv8;
typedef __attribute__((ext_vector_type(8))) short sv8;
typedef __attribute__((ext_vector_type(4))) unsigned short usv4;

// ---------------- helpers ----------------

static __device__ __forceinline__ f32x4 mfma16(sv8 a, sv8 b, f32x4 c) {
    return __builtin_amdgcn_mfma_f32_16x16x32_bf16(
        __builtin_bit_cast(bfv8, a), __builtin_bit_cast(bfv8, b), c, 0, 0, 0);
}

static __device__ __forceinline__ unsigned short f2bf(float f) {
    union { float f; unsigned int u; } v; v.f = f;
    unsigned int u = v.u;
    return (unsigned short)((u + 0x7FFFu + ((u >> 16) & 1u)) >> 16);  // RNE
}

// async global->LDS, 16B per lane (dest linear in lane order)
static __device__ __forceinline__ void gld16(void* lds, const void* g) {
    __builtin_amdgcn_global_load_lds(
        (const __attribute__((address_space(1))) unsigned int*)g,
        (__attribute__((address_space(3))) unsigned int*)lds, 16, 0, 0);
}

// ---------------- fp32 -> bf16 convert (weights) ----------------

__global__ void cvt_bf16_kernel(const float* __restrict__ in,
                                unsigned short* __restrict__ out, int n4) {
    int i = blockIdx.x * 256 + threadIdx.x;
    if (i >= n4) return;
    float4 f = reinterpret_cast<const float4*>(in)[i];
    usv4 o = { f2bf(f.x), f2bf(f.y), f2bf(f.z), f2bf(f.w) };
    reinterpret_cast<usv4*>(out)[i] = o;
}

// ---------------- LayerNorm fp32 -> bf16, C=768 ----------------

__global__ void ln_kernel(const float* __restrict__ x, const float* __restrict__ w,
                          const float* __restrict__ b, unsigned short* __restrict__ out) {
    const int row = blockIdx.x;
    const int t = threadIdx.x;
    const float* xr = x + (size_t)row * 768;
    float v[3];
    float s = 0.f, ss = 0.f;
#pragma unroll
    for (int i = 0; i < 3; ++i) {
        v[i] = xr[t + i * 256];
        s += v[i]; ss += v[i] * v[i];
    }
#pragma unroll
    for (int o = 32; o; o >>= 1) { s += __shfl_xor(s, o); ss += __shfl_xor(ss, o); }
    __shared__ float red[8];
    if ((t & 63) == 0) { red[t >> 6] = s; red[4 + (t >> 6)] = ss; }
    __syncthreads();
    float S = red[0] + red[1] + red[2] + red[3];
    float SS = red[4] + red[5] + red[6] + red[7];
    float mu = S * (1.0f / 768.0f);
    float var = SS * (1.0f / 768.0f) - mu * mu;
    float rstd = rsqrtf(var + 1e-6f);
#pragma unroll
    for (int i = 0; i < 3; ++i) {
        int c = t + i * 256;
        out[(size_t)row * 768 + c] = f2bf((v[i] - mu) * rstd * w[c] + b[c]);
    }
}

// ---------------- prompt [B,20,2,H,64] fp32 -> K [B,H,224,64], Vt [B,H,64,224] bf16 ----------------

__global__ void prompt_kernel(const float* __restrict__ pr,
                              unsigned short* __restrict__ k_out,
                              unsigned short* __restrict__ v_out) {
    int i = blockIdx.x * 256 + threadIdx.x;  // over B*P*H*64 = 983040
    if (i >= 64 * 20 * 12 * 64) return;
    int d = i & 63;
    int t = i >> 6;
    int h = t % 12;
    int t2 = t / 12;
    int p = t2 % 20;
    int b = t2 / 20;
    size_t src = ((((size_t)b * 20 + p) * 2 + 0) * 12 + h) * 64 + d;
    float kv = pr[src];
    float vv = pr[src + 12 * 64];  // s=1 plane
    k_out[(((size_t)(b * 12 + h) * 224 + p) << 6) + d] = f2bf(kv);
    v_out[((size_t)(b * 12 + h) * 64 + d) * 224 + p] = f2bf(vv);
}

#define EPI_QKV 0
#define EPI_RES 1
#define EPI_GELU 2

// ---------------- epilogue (shared by both GEMM variants) ----------------

template <int EPI>
static __device__ __forceinline__ void gemm_epilogue(
        f32x4 (&acc)[4][4], int bmBase, int bnBase, int wm, int wn,
        int rl, int kg, const float* bias, const float* resid, void* out0,
        unsigned short* q_out, unsigned short* k_out, unsigned short* v_out,
        int M, int N) {
#pragma unroll
    for (int i = 0; i < 4; ++i) {
        const int m0 = bmBase + wm * 64 + i * 16 + kg * 4;
#pragma unroll
        for (int j = 0; j < 4; ++j) {
            const int ncol = bnBase + wn * 64 + j * 16 + rl;
            const float bia = bias[ncol];
#pragma unroll
            for (int r = 0; r < 4; ++r) {
                const int m = m0 + r;
                if (m >= M) continue;
                float vv = acc[i][j][r] + bia;
                if constexpr (EPI == EPI_QKV) {
                    int b = m / 197, nn = m - b * 197;
                    int which = ncol / 768;
                    int rc = ncol - which * 768;
                    int h = rc >> 6;
                    int d = ncol & 63;
                    if (which == 0)
                        q_out[(((size_t)(b * 12 + h) * 197 + nn) << 6) + d] = f2bf(vv);
                    else if (which == 1)
                        k_out[(((size_t)(b * 12 + h) * 224 + 20 + nn) << 6) + d] = f2bf(vv);
                    else
                        v_out[((size_t)(b * 12 + h) * 64 + d) * 224 + 20 + nn] = f2bf(vv);
                } else if constexpr (EPI == EPI_RES) {
                    ((float*)out0)[(size_t)m * N + ncol] = vv + resid[(size_t)m * N + ncol];
                } else {  // GELU tanh-approx in sigmoid form
                    float g = vv / (1.0f + __expf(-1.5957691216f * vv * (1.0f + 0.044715f * vv * vv)));
                    ((unsigned short*)out0)[(size_t)m * N + ncol] = f2bf(g);
                }
            }
        }
    }
}

// ---------------- r11-proven synced GEMM (controls: qkv, proj) ----------------
// Tile (WM*64) x (WN*64), per-wave 64x64. 2-buffer LDS, stage-early, one barrier/iter.

template <int EPI, int WM, int WN>
__global__ void __launch_bounds__(WM * WN * 64)
gemm_bf16(const unsigned short* __restrict__ A,
          const unsigned short* __restrict__ W,
          const float* __restrict__ bias,
          const float* __restrict__ resid,
          void* __restrict__ out0,
          unsigned short* __restrict__ q_out,
          unsigned short* __restrict__ k_out,
          unsigned short* __restrict__ v_out,
          int M, int N, int K, int NB) {
    constexpr int THREADS = WM * WN * 64;
    constexpr int BM = WM * 64, BN = WN * 64;
    constexpr int NCA = (BM * 4) / THREADS;
    constexpr int NCB = (BN * 4) / THREADS;
    __shared__ __align__(16) unsigned short As[2][BM * 32];
    __shared__ __align__(16) unsigned short Bs[2][BN * 32];
    const int tid = threadIdx.x;
    const int lane = tid & 63;
    const int wv = tid >> 6;
    const int wm = wv / WN, wn = wv % WN;
    const int rl = lane & 15, kg = lane >> 4;

    const int nwg = gridDim.x;
    const int orig = blockIdx.x;
    const int xcd = orig & 7;
    const int qq = nwg >> 3, rr = nwg & 7;
    const int wg = (xcd < rr ? xcd * (qq + 1) : rr * (qq + 1) + (xcd - rr) * qq) + (orig >> 3);
    const int bm = wg / NB, bn = wg - bm * NB;

    const unsigned short* pA[NCA];
    const unsigned short* pB[NCB];
#pragma unroll
    for (int i = 0; i < NCA; ++i) {
        const int c = i * THREADS + tid;
        const int row = c >> 2, sl = c & 3;
        int ar = bm * BM + row; ar = ar < M ? ar : M - 1;
        pA[i] = A + (size_t)ar * K + sl * 8;
    }
#pragma unroll
    for (int i = 0; i < NCB; ++i) {
        const int c = i * THREADS + tid;
        const int row = c >> 2, sl = c & 3;
        pB[i] = W + (size_t)(bn * BN + row) * K + sl * 8;
    }
    auto stage = [&](int sb, int kt) {
        const int k0 = kt << 5;
#pragma unroll
        for (int i = 0; i < NCA; ++i)
            gld16(&As[sb][(i * THREADS + tid) * 8], pA[i] + k0);
#pragma unroll
        for (int i = 0; i < NCB; ++i)
            gld16(&Bs[sb][(i * THREADS + tid) * 8], pB[i] + k0);
    };

    f32x4 acc[4][4];
#pragma unroll
    for (int i = 0; i < 4; ++i)
#pragma unroll
        for (int j = 0; j < 4; ++j) acc[i][j] = f32x4{0.f, 0.f, 0.f, 0.f};

    const int nk = K >> 5;
    stage(0, 0);
    __syncthreads();
    for (int kt = 0; kt < nk; ++kt) {
        const int cur = kt & 1;
        if (kt + 1 < nk) stage(cur ^ 1, kt + 1);
        sv8 af[4], bfr[4];
#pragma unroll
        for (int f = 0; f < 4; ++f) {
            const int ra = wm * 64 + f * 16 + rl;
            af[f] = *reinterpret_cast<const sv8*>(&As[cur][ra * 32 + kg * 8]);
            const int rb = wn * 64 + f * 16 + rl;
            bfr[f] = *reinterpret_cast<const sv8*>(&Bs[cur][rb * 32 + kg * 8]);
        }
#pragma unroll
        for (int i = 0; i < 4; ++i)
#pragma unroll
            for (int j = 0; j < 4; ++j) acc[i][j] = mfma16(af[i], bfr[j], acc[i][j]);
        __syncthreads();
    }
    gemm_epilogue<EPI>(acc, bm * BM, bn * BN, wm, wn, rl, kg, bias, resid,
                       out0, q_out, k_out, v_out, M, N);
}

// ---------------- r14: wave-private BARRIER-FREE GEMM (fc1, fc2) ----------------
// Diagnosis (r5-r13): every synced variant pins at ~450 TF with MfmaUtil 13-19% while
// no pipe (LDS/L2/HBM/MFMA/VALU) is near saturation -> the per-iter __syncthreads
// phase-aligns all resident waves (all ds_read together, all MFMA together, all drain
// together) = anti-pipelining. Fix: each wave stages ITS OWN A-half + B-half into
// private LDS (8KB/iter, x2 duplication across the 2 waves sharing a row/col-half) and
// synchronizes ONLY on its own counters. Zero barriers -> waves drift -> CU pipes
// (VMEM, LDS, MFMA) interleave across 8 free-running waves.
// Ledger (per wave, FIFO vmcnt): iter t top: outstanding = stage(t+1)[8] (+tail of
// stage(t)); vmcnt(8) => stage(t) complete (vmcnt(0) for the last iter). lgkmcnt(0)
// before re-staging buf(cur) for t+2 clears the WAR on just-issued ds_reads. LDS 64KB
// -> 2 blocks/CU. Grid: 1-D, XCD swizzle, bn-fastest.

template <int EPI>
__global__ void __launch_bounds__(256)
gemm_wp(const unsigned short* __restrict__ A,
        const unsigned short* __restrict__ W,
        const float* __restrict__ bias,
        const float* __restrict__ resid,
        void* __restrict__ out0,
        int M, int N, int K, int NB) {
    __shared__ __align__(16) unsigned short L[2][4][4096];  // [buf][wave][A:0..2047 | B:2048..4095]
    const int tid = threadIdx.x;
    const int lane = tid & 63;
    const int wave = tid >> 6;
    const int wm = wave >> 1, wn = wave & 1;
    const int rl = lane & 15, kg = lane >> 4;

    const int nwg = gridDim.x;
    const int orig = blockIdx.x;
    const int xcd = orig & 7;
    const int qq = nwg >> 3, rr = nwg & 7;
    const int wg = (xcd < rr ? xcd * (qq + 1) : rr * (qq + 1) + (xcd - rr) * qq) + (orig >> 3);
    const int bm = wg / NB, bn = wg - bm * NB;

    // per-wave stage pointers: chunk c = i*64+lane (0..255): row=c>>2, slot=c&3
    const unsigned short* gA[4];
    const unsigned short* gB[4];
#pragma unroll
    for (int i = 0; i < 4; ++i) {
        const int c = i * 64 + lane;
        const int row = c >> 2, sl = c & 3;
        int ar = bm * 128 + wm * 64 + row; ar = ar < M ? ar : M - 1;
        gA[i] = A + (size_t)ar * K + sl * 8;
        gB[i] = W + (size_t)(bn * 128 + wn * 64 + row) * K + sl * 8;
    }
    unsigned short* myL0 = &L[0][wave][0];
    unsigned short* myL1 = &L[1][wave][0];

    auto stage = [&](int sb, int kt) {   // 8 gld16, wave-private dest
        unsigned short* base = sb ? myL1 : myL0;
        const int k0 = kt << 5;
#pragma unroll
        for (int i = 0; i < 4; ++i) {
            const int c8 = (i * 64 + lane) * 8;
            gld16(base + c8, gA[i] + k0);
            gld16(base + 2048 + c8, gB[i] + k0);
        }
    };

    f32x4 acc[4][4];
#pragma unroll
    for (int i = 0; i < 4; ++i)
#pragma unroll
        for (int j = 0; j < 4; ++j) acc[i][j] = f32x4{0.f, 0.f, 0.f, 0.f};

    const int nk = K >> 5;   // >= 24
    stage(0, 0);
    stage(1, 1);
    for (int kt = 0; kt < nk; ++kt) {
        const int cur = kt & 1;
        if (kt + 1 < nk)
            asm volatile("s_waitcnt vmcnt(8)" ::: "memory");  // buf(cur) staged (FIFO)
        else
            asm volatile("s_waitcnt vmcnt(0)" ::: "memory");  // last buf
        const unsigned short* base = cur ? myL1 : myL0;
        sv8 af[4], bfr[4];
#pragma unroll
        for (int f = 0; f < 4; ++f) {
            af[f]  = *reinterpret_cast<const sv8*>(base + (f * 16 + rl) * 32 + kg * 8);
            bfr[f] = *reinterpret_cast<const sv8*>(base + 2048 + (f * 16 + rl) * 32 + kg * 8);
        }
        if (kt + 2 < nk) {
            asm volatile("s_waitcnt lgkmcnt(0)" ::: "memory");  // reads retired (WAR)
            stage(cur, kt + 2);
        }
#pragma unroll
        for (int i = 0; i < 4; ++i)
#pragma unroll
            for (int j = 0; j < 4; ++j) acc[i][j] = mfma16(af[i], bfr[j], acc[i][j]);
    }
    gemm_epilogue<EPI>(acc, bm * 128, bn * 128, wm, wn, rl, kg, bias, resid,
                       out0, nullptr, nullptr, nullptr, M, N);
}

// ---------------- attention: per (b,h,qtile64): S=QK^T, softmax, O=PV ----------------

__global__ void attn_kernel(const unsigned short* __restrict__ Qg,
                            const unsigned short* __restrict__ Kg,
                            const unsigned short* __restrict__ Vtg,
                            unsigned short* __restrict__ obuf) {
    __shared__ __align__(16) unsigned short sKS[14848];  // max(224*64, 4*16*232)
    __shared__ __align__(16) unsigned short sV[64 * 232];
    const int tid = threadIdx.x;
    const int lane = tid & 63;
    const int wave = tid >> 6;
    const int rl = lane & 15, kg = lane >> 4;
    const int qt = blockIdx.x, h = blockIdx.y, b = blockIdx.z;
    const size_t bh = (size_t)b * 12 + h;
    const size_t qbase = bh * 197 * 64;
    const size_t kbase = bh * 224 * 64;
    const size_t vbase = bh * 64 * 224;

    int qrow = qt * 64 + wave * 16 + rl;
    if (qrow > 196) qrow = 196;
    sv8 qf[2];
#pragma unroll
    for (int ks = 0; ks < 2; ++ks)
        qf[ks] = *reinterpret_cast<const sv8*>(&Qg[qbase + (size_t)qrow * 64 + ks * 32 + kg * 8]);

#pragma unroll
    for (int i = 0; i < 7; ++i) {
        const int c = i * 256 + tid;       // 1792 chunks of 16B
        const int key = c >> 3, sl = c & 7;
        const int ssl = sl ^ (key & 7);
        gld16(&sKS[c * 8], &Kg[kbase + key * 64 + ssl * 8]);
    }
#pragma unroll
    for (int i = 0; i < 7; ++i) {
        const int c = i * 256 + tid;
        const int d = c / 28, sl = c - d * 28;
        sv8 val = *reinterpret_cast<const sv8*>(&Vtg[vbase + d * 224 + sl * 8]);
        *reinterpret_cast<sv8*>(&sV[d * 232 + sl * 8]) = val;
    }
    __syncthreads();

    f32x4 sacc[14];
#pragma unroll
    for (int f = 0; f < 14; ++f) sacc[f] = f32x4{0.f, 0.f, 0.f, 0.f};
#pragma unroll
    for (int f = 0; f < 14; ++f) {
        const int key = f * 16 + rl;
#pragma unroll
        for (int ks = 0; ks < 2; ++ks) {
            const int sl = (ks * 4 + kg) ^ (key & 7);
            sv8 kf = *reinterpret_cast<const sv8*>(&sKS[key * 64 + sl * 8]);
            sacc[f] = mfma16(qf[ks], kf, sacc[f]);
        }
    }

    float mx[4] = {-1e30f, -1e30f, -1e30f, -1e30f};
#pragma unroll
    for (int f = 0; f < 14; ++f) {
        const int col = f * 16 + rl;
#pragma unroll
        for (int r = 0; r < 4; ++r) {
            float s = sacc[f][r] * 0.125f;
            if (col >= 217) s = -1e30f;
            sacc[f][r] = s;
            mx[r] = fmaxf(mx[r], s);
        }
    }
#pragma unroll
    for (int o = 1; o < 16; o <<= 1)
#pragma unroll
        for (int r = 0; r < 4; ++r) mx[r] = fmaxf(mx[r], __shfl_xor(mx[r], o));
    float sm[4] = {0.f, 0.f, 0.f, 0.f};
#pragma unroll
    for (int f = 0; f < 14; ++f)
#pragma unroll
        for (int r = 0; r < 4; ++r) {
            float e = __expf(sacc[f][r] - mx[r]);
            sacc[f][r] = e;
            sm[r] += e;
        }
#pragma unroll
    for (int o = 1; o < 16; o <<= 1)
#pragma unroll
        for (int r = 0; r < 4; ++r) sm[r] += __shfl_xor(sm[r], o);
    float inv[4];
#pragma unroll
    for (int r = 0; r < 4; ++r) inv[r] = 1.0f / sm[r];

    __syncthreads();
    unsigned short* Sl = sKS;  // S [4 waves][16 q][232]
#pragma unroll
    for (int f = 0; f < 14; ++f)
#pragma unroll
        for (int r = 0; r < 4; ++r)
            Sl[(wave * 16 + kg * 4 + r) * 232 + f * 16 + rl] = f2bf(sacc[f][r] * inv[r]);
    __syncthreads();

    f32x4 oacc[4];
#pragma unroll
    for (int fd = 0; fd < 4; ++fd) oacc[fd] = f32x4{0.f, 0.f, 0.f, 0.f};
#pragma unroll
    for (int ks = 0; ks < 7; ++ks) {
        sv8 pf = *reinterpret_cast<const sv8*>(&Sl[(wave * 16 + rl) * 232 + ks * 32 + kg * 8]);
#pragma unroll
        for (int fd = 0; fd < 4; ++fd) {
            sv8 vf = *reinterpret_cast<const sv8*>(&sV[(fd * 16 + rl) * 232 + ks * 32 + kg * 8]);
            oacc[fd] = mfma16(pf, vf, oacc[fd]);
        }
    }

#pragma unroll
    for (int fd = 0; fd < 4; ++fd)
#pragma unroll
        for (int r = 0; r < 4; ++r) {
            const int q = qt * 64 + wave * 16 + kg * 4 + r;
            if (q < 197)
                obuf[((size_t)b * 197 + q) * 768 + h * 64 + fd * 16 + rl] = f2bf(oacc[fd][r]);
        }
}

// ---------------- host ----------------

extern "C" void kernel_launch(void* const* d_in, const int* in_sizes, int n_in,
                              void* d_out, int out_size, void* d_ws, size_t ws_size,
                              hipStream_t stream) {
    const float* x      = (const float*)d_in[0];
    const float* prompt = (const float*)d_in[1];
    const float* ln1_w  = (const float*)d_in[2];
    const float* ln1_b  = (const float*)d_in[3];
    const float* qkv_w  = (const float*)d_in[4];
    const float* qkv_b  = (const float*)d_in[5];
    const float* proj_w = (const float*)d_in[6];
    const float* proj_b = (const float*)d_in[7];
    const float* ln2_w  = (const float*)d_in[8];
    const float* ln2_b  = (const float*)d_in[9];
    const float* fc1_w  = (const float*)d_in[10];
    const float* fc1_b  = (const float*)d_in[11];
    const float* fc2_w  = (const float*)d_in[12];
    const float* fc2_b  = (const float*)d_in[13];

    char* ws = (char*)d_ws;
    size_t off = 0;
    auto bump = [&](size_t bytes) {
        char* p = ws + off;
        off += (bytes + 255) & ~(size_t)255;
        return p;
    };
    unsigned short* qkvw  = (unsigned short*)bump(2304UL * 768 * 2);
    unsigned short* projw = (unsigned short*)bump(768UL * 768 * 2);
    unsigned short* fc1w  = (unsigned short*)bump(3072UL * 768 * 2);
    unsigned short* fc2w  = (unsigned short*)bump(768UL * 3072 * 2);
    unsigned short* h2    = (unsigned short*)bump(12608UL * 768 * 2);
    float* xmid           = (float*)bump(12608UL * 768 * 4);
    char* pool = ws + off;
    unsigned short* h1   = (unsigned short*)(pool);
    unsigned short* Qg   = (unsigned short*)(pool + 19365888UL);
    unsigned short* Kg   = (unsigned short*)(pool + 38731776UL);
    unsigned short* Vtg  = (unsigned short*)(pool + 60751872UL);
    unsigned short* obuf = (unsigned short*)(pool + 82771968UL);
    unsigned short* mbuf = (unsigned short*)(pool);  // aliases h1/Q/K/Vt (dead by fc1)

    cvt_bf16_kernel<<<(2304 * 768 / 4 + 255) / 256, 256, 0, stream>>>(qkv_w, qkvw, 2304 * 768 / 4);
    cvt_bf16_kernel<<<(768 * 768 / 4 + 255) / 256, 256, 0, stream>>>(proj_w, projw, 768 * 768 / 4);
    cvt_bf16_kernel<<<(3072 * 768 / 4 + 255) / 256, 256, 0, stream>>>(fc1_w, fc1w, 3072 * 768 / 4);
    cvt_bf16_kernel<<<(768 * 3072 / 4 + 255) / 256, 256, 0, stream>>>(fc2_w, fc2w, 768 * 3072 / 4);

    ln_kernel<<<12608, 256, 0, stream>>>(x, ln1_w, ln1_b, h1);
    prompt_kernel<<<983040 / 256, 256, 0, stream>>>(prompt, Kg, Vtg);

    // qkv: control (r11 config, 256x128 tiles)
    gemm_bf16<EPI_QKV, 4, 2><<<50 * 18, 512, 0, stream>>>(
        h1, qkvw, qkv_b, nullptr, nullptr, Qg, Kg, Vtg, 12608, 2304, 768, 18);

    attn_kernel<<<dim3(4, 12, 64), 256, 0, stream>>>(Qg, Kg, Vtg, obuf);

    // proj: control (r10/r11 config, 128^2)
    gemm_bf16<EPI_RES, 2, 2><<<99 * 6, 256, 0, stream>>>(
        obuf, projw, proj_b, x, xmid, nullptr, nullptr, nullptr, 12608, 768, 768, 6);

    ln_kernel<<<12608, 256, 0, stream>>>(xmid, ln2_w, ln2_b, h2);

    // fc1: wave-private barrier-free
    gemm_wp<EPI_GELU><<<99 * 24, 256, 0, stream>>>(
        h2, fc1w, fc1_b, nullptr, mbuf, 12608, 3072, 768, 24);

    // fc2: wave-private barrier-free, K=3072
    gemm_wp<EPI_RES><<<99 * 6, 256, 0, stream>>>(
        mbuf, fc2w, fc2_b, xmid, (float*)d_out, 12608, 768, 3072, 6);
}

// Round 15
// 410.585 us; speedup vs baseline: 1.3078x; 1.3078x over previous
//
#include <hip/hip_runtime.h>
#include <hip/hip_bf16.h>

typedef __attribute__((ext_vector_type(4))) float f32x4;
typedef __attribute__((ext_vector_type(8))) __bf16 bfv8;
typedef __attribute__((ext_vector_type(8))) short sv8;
typedef __attribute__((ext_vector_type(4))) unsigned short usv4;

// ---------------- helpers ----------------

static __device__ __forceinline__ f32x4 mfma16(sv8 a, sv8 b, f32x4 c) {
    return __builtin_amdgcn_mfma_f32_16x16x32_bf16(
        __builtin_bit_cast(bfv8, a), __builtin_bit_cast(bfv8, b), c, 0, 0, 0);
}

static __device__ __forceinline__ unsigned short f2bf(float f) {
    union { float f; unsigned int u; } v; v.f = f;
    unsigned int u = v.u;
    return (unsigned short)((u + 0x7FFFu + ((u >> 16) & 1u)) >> 16);  // RNE
}

// async global->LDS, 16B per lane (dest linear in lane order)
static __device__ __forceinline__ void gld16(void* lds, const void* g) {
    __builtin_amdgcn_global_load_lds(
        (const __attribute__((address_space(1))) unsigned int*)g,
        (__attribute__((address_space(3))) unsigned int*)lds, 16, 0, 0);
}

// ---------------- vectorized LayerNorm row: 192 active lanes x float4 ----------------

static __device__ __forceinline__ void ln_row(const float* __restrict__ xr,
                                              const float* __restrict__ w,
                                              const float* __restrict__ b,
                                              unsigned short* __restrict__ outr,
                                              int t) {
    __shared__ float red[8];
    float4 v = {0.f, 0.f, 0.f, 0.f};
    float s = 0.f, ss = 0.f;
    if (t < 192) {
        v = reinterpret_cast<const float4*>(xr)[t];
        s = v.x + v.y + v.z + v.w;
        ss = v.x * v.x + v.y * v.y + v.z * v.z + v.w * v.w;
    }
#pragma unroll
    for (int o = 32; o; o >>= 1) { s += __shfl_xor(s, o); ss += __shfl_xor(ss, o); }
    if ((t & 63) == 0) { red[t >> 6] = s; red[4 + (t >> 6)] = ss; }
    __syncthreads();
    const float S = red[0] + red[1] + red[2];
    const float SS = red[4] + red[5] + red[6];
    const float mu = S * (1.0f / 768.0f);
    const float var = SS * (1.0f / 768.0f) - mu * mu;
    const float rstd = rsqrtf(var + 1e-6f);
    if (t < 192) {
        float4 wv = reinterpret_cast<const float4*>(w)[t];
        float4 bv = reinterpret_cast<const float4*>(b)[t];
        usv4 o = { f2bf((v.x - mu) * rstd * wv.x + bv.x),
                   f2bf((v.y - mu) * rstd * wv.y + bv.y),
                   f2bf((v.z - mu) * rstd * wv.z + bv.z),
                   f2bf((v.w - mu) * rstd * wv.w + bv.w) };
        reinterpret_cast<usv4*>(outr)[t] = o;
    }
}

__global__ void ln_kernel(const float* __restrict__ x, const float* __restrict__ w,
                          const float* __restrict__ b, unsigned short* __restrict__ out) {
    const size_t row = blockIdx.x;
    ln_row(x + row * 768, w, b, out + row * 768, threadIdx.x);
}

// ---------------- fused prep: 4x weight-cvt + prompt rearrange + LN1 ----------------
// Segments (blocks of 256 threads, all exactly divisible -> no bounds checks):
//   [0, 1728)        qkv_w cvt    (442368 float4)
//   [1728, 2304)     proj_w cvt   (147456)
//   [2304, 4608)     fc1_w cvt    (589824)
//   [4608, 6912)     fc2_w cvt    (589824)
//   [6912, 10752)    prompt       (983040 elems)
//   [10752, 23360)   LN1          (12608 rows)

__global__ void prep_kernel(const float* __restrict__ qkv_w, const float* __restrict__ proj_w,
                            const float* __restrict__ fc1_w, const float* __restrict__ fc2_w,
                            unsigned short* __restrict__ qkvw, unsigned short* __restrict__ projw,
                            unsigned short* __restrict__ fc1w, unsigned short* __restrict__ fc2w,
                            const float* __restrict__ pr,
                            unsigned short* __restrict__ k_out, unsigned short* __restrict__ v_out,
                            const float* __restrict__ x, const float* __restrict__ ln1_w,
                            const float* __restrict__ ln1_b, unsigned short* __restrict__ h1) {
    const int blk = blockIdx.x;
    const int tid = threadIdx.x;
    if (blk < 6912) {
        const float* in;
        unsigned short* out;
        int i;
        if (blk < 1728)      { in = qkv_w; out = qkvw; i = blk * 256 + tid; }
        else if (blk < 2304) { in = proj_w; out = projw; i = (blk - 1728) * 256 + tid; }
        else if (blk < 4608) { in = fc1_w; out = fc1w; i = (blk - 2304) * 256 + tid; }
        else                 { in = fc2_w; out = fc2w; i = (blk - 4608) * 256 + tid; }
        float4 f = reinterpret_cast<const float4*>(in)[i];
        usv4 o = { f2bf(f.x), f2bf(f.y), f2bf(f.z), f2bf(f.w) };
        reinterpret_cast<usv4*>(out)[i] = o;
    } else if (blk < 10752) {
        const int i = (blk - 6912) * 256 + tid;   // over B*P*H*64 = 983040
        const int d = i & 63;
        const int t = i >> 6;
        const int h = t % 12;
        const int t2 = t / 12;
        const int p = t2 % 20;
        const int b = t2 / 20;
        size_t src = ((((size_t)b * 20 + p) * 2 + 0) * 12 + h) * 64 + d;
        float kv = pr[src];
        float vv = pr[src + 12 * 64];  // s=1 plane
        k_out[(((size_t)(b * 12 + h) * 224 + p) << 6) + d] = f2bf(kv);
        v_out[((size_t)(b * 12 + h) * 64 + d) * 224 + p] = f2bf(vv);
    } else {
        const size_t row = blk - 10752;
        ln_row(x + row * 768, ln1_w, ln1_b, h1 + row * 768, tid);
    }
}

#define EPI_QKV 0
#define EPI_RES 1
#define EPI_GELU 2

// ---------------- epilogue ----------------

template <int EPI>
static __device__ __forceinline__ void gemm_epilogue(
        f32x4 (&acc)[4][4], int bmBase, int bnBase, int wm, int wn,
        int rl, int kg, const float* bias, const float* resid, void* out0,
        unsigned short* q_out, unsigned short* k_out, unsigned short* v_out,
        int M, int N) {
#pragma unroll
    for (int i = 0; i < 4; ++i) {
        const int m0 = bmBase + wm * 64 + i * 16 + kg * 4;
#pragma unroll
        for (int j = 0; j < 4; ++j) {
            const int ncol = bnBase + wn * 64 + j * 16 + rl;
            const float bia = bias[ncol];
#pragma unroll
            for (int r = 0; r < 4; ++r) {
                const int m = m0 + r;
                if (m >= M) continue;
                float vv = acc[i][j][r] + bia;
                if constexpr (EPI == EPI_QKV) {
                    int b = m / 197, nn = m - b * 197;
                    int which = ncol / 768;
                    int rc = ncol - which * 768;
                    int h = rc >> 6;
                    int d = ncol & 63;
                    if (which == 0)
                        q_out[(((size_t)(b * 12 + h) * 197 + nn) << 6) + d] = f2bf(vv);
                    else if (which == 1)
                        k_out[(((size_t)(b * 12 + h) * 224 + 20 + nn) << 6) + d] = f2bf(vv);
                    else
                        v_out[((size_t)(b * 12 + h) * 64 + d) * 224 + 20 + nn] = f2bf(vv);
                } else if constexpr (EPI == EPI_RES) {
                    ((float*)out0)[(size_t)m * N + ncol] = vv + resid[(size_t)m * N + ncol];
                } else {  // GELU tanh-approx in sigmoid form
                    float g = vv / (1.0f + __expf(-1.5957691216f * vv * (1.0f + 0.044715f * vv * vv)));
                    ((unsigned short*)out0)[(size_t)m * N + ncol] = f2bf(g);
                }
            }
        }
    }
}

// ---------------- r11-best synced GEMM: tile (WM*64) x (WN*64), per-wave 64x64 ----------------
// 2-buffer LDS, stage(t+1) at iter start, one __syncthreads per iter. Linear staging.
// Shape-plateau note (r5-r14): ~370 cy per 16-MFMA wave-iter per CU for this shape class,
// invariant under occupancy/BK/depth/swizzle/L2-tiling/tile-aspect/barrier-removal; matches
// the guide's m102 shape curve (sub-4k shapes ~320-450 TF for 2-phase structures).

template <int EPI, int WM, int WN>
__global__ void __launch_bounds__(WM * WN * 64)
gemm_bf16(const unsigned short* __restrict__ A,
          const unsigned short* __restrict__ W,
          const float* __restrict__ bias,
          const float* __restrict__ resid,
          void* __restrict__ out0,
          unsigned short* __restrict__ q_out,
          unsigned short* __restrict__ k_out,
          unsigned short* __restrict__ v_out,
          int M, int N, int K, int NB) {
    constexpr int THREADS = WM * WN * 64;
    constexpr int BM = WM * 64, BN = WN * 64;
    constexpr int NCA = (BM * 4) / THREADS;
    constexpr int NCB = (BN * 4) / THREADS;
    __shared__ __align__(16) unsigned short As[2][BM * 32];
    __shared__ __align__(16) unsigned short Bs[2][BN * 32];
    const int tid = threadIdx.x;
    const int lane = tid & 63;
    const int wv = tid >> 6;
    const int wm = wv / WN, wn = wv % WN;
    const int rl = lane & 15, kg = lane >> 4;

    // bijective XCD swizzle (m204); wg increases bn-fastest (bm = wg/NB)
    const int nwg = gridDim.x;
    const int orig = blockIdx.x;
    const int xcd = orig & 7;
    const int qq = nwg >> 3, rr = nwg & 7;
    const int wg = (xcd < rr ? xcd * (qq + 1) : rr * (qq + 1) + (xcd - rr) * qq) + (orig >> 3);
    const int bm = wg / NB, bn = wg - bm * NB;

    const unsigned short* pA[NCA];
    const unsigned short* pB[NCB];
#pragma unroll
    for (int i = 0; i < NCA; ++i) {
        const int c = i * THREADS + tid;
        const int row = c >> 2, sl = c & 3;
        int ar = bm * BM + row; ar = ar < M ? ar : M - 1;
        pA[i] = A + (size_t)ar * K + sl * 8;
    }
#pragma unroll
    for (int i = 0; i < NCB; ++i) {
        const int c = i * THREADS + tid;
        const int row = c >> 2, sl = c & 3;
        pB[i] = W + (size_t)(bn * BN + row) * K + sl * 8;
    }
    auto stage = [&](int sb, int kt) {
        const int k0 = kt << 5;
#pragma unroll
        for (int i = 0; i < NCA; ++i)
            gld16(&As[sb][(i * THREADS + tid) * 8], pA[i] + k0);
#pragma unroll
        for (int i = 0; i < NCB; ++i)
            gld16(&Bs[sb][(i * THREADS + tid) * 8], pB[i] + k0);
    };

    f32x4 acc[4][4];
#pragma unroll
    for (int i = 0; i < 4; ++i)
#pragma unroll
        for (int j = 0; j < 4; ++j) acc[i][j] = f32x4{0.f, 0.f, 0.f, 0.f};

    const int nk = K >> 5;
    stage(0, 0);
    __syncthreads();
    for (int kt = 0; kt < nk; ++kt) {
        const int cur = kt & 1;
        if (kt + 1 < nk) stage(cur ^ 1, kt + 1);   // issue next-tile loads EARLY
        sv8 af[4], bfr[4];
#pragma unroll
        for (int f = 0; f < 4; ++f) {
            const int ra = wm * 64 + f * 16 + rl;
            af[f] = *reinterpret_cast<const sv8*>(&As[cur][ra * 32 + kg * 8]);
            const int rb = wn * 64 + f * 16 + rl;
            bfr[f] = *reinterpret_cast<const sv8*>(&Bs[cur][rb * 32 + kg * 8]);
        }
#pragma unroll
        for (int i = 0; i < 4; ++i)
#pragma unroll
            for (int j = 0; j < 4; ++j) acc[i][j] = mfma16(af[i], bfr[j], acc[i][j]);
        __syncthreads();   // drains vmcnt (next buf staged) + lgkm; one barrier/iter
    }
    gemm_epilogue<EPI>(acc, bm * BM, bn * BN, wm, wn, rl, kg, bias, resid,
                       out0, q_out, k_out, v_out, M, N);
}

// ---------------- attention: per (b,h,qtile64): S=QK^T, softmax, O=PV ----------------

__global__ void attn_kernel(const unsigned short* __restrict__ Qg,
                            const unsigned short* __restrict__ Kg,
                            const unsigned short* __restrict__ Vtg,
                            unsigned short* __restrict__ obuf) {
    __shared__ __align__(16) unsigned short sKS[14848];  // max(224*64, 4*16*232)
    __shared__ __align__(16) unsigned short sV[64 * 232];
    const int tid = threadIdx.x;
    const int lane = tid & 63;
    const int wave = tid >> 6;
    const int rl = lane & 15, kg = lane >> 4;
    const int qt = blockIdx.x, h = blockIdx.y, b = blockIdx.z;
    const size_t bh = (size_t)b * 12 + h;
    const size_t qbase = bh * 197 * 64;
    const size_t kbase = bh * 224 * 64;
    const size_t vbase = bh * 64 * 224;

    int qrow = qt * 64 + wave * 16 + rl;
    if (qrow > 196) qrow = 196;
    sv8 qf[2];
#pragma unroll
    for (int ks = 0; ks < 2; ++ks)
        qf[ks] = *reinterpret_cast<const sv8*>(&Qg[qbase + (size_t)qrow * 64 + ks * 32 + kg * 8]);

#pragma unroll
    for (int i = 0; i < 7; ++i) {
        const int c = i * 256 + tid;       // 1792 chunks of 16B
        const int key = c >> 3, sl = c & 7;
        const int ssl = sl ^ (key & 7);
        gld16(&sKS[c * 8], &Kg[kbase + key * 64 + ssl * 8]);
    }
#pragma unroll
    for (int i = 0; i < 7; ++i) {
        const int c = i * 256 + tid;
        const int d = c / 28, sl = c - d * 28;
        sv8 val = *reinterpret_cast<const sv8*>(&Vtg[vbase + d * 224 + sl * 8]);
        *reinterpret_cast<sv8*>(&sV[d * 232 + sl * 8]) = val;
    }
    __syncthreads();

    f32x4 sacc[14];
#pragma unroll
    for (int f = 0; f < 14; ++f) sacc[f] = f32x4{0.f, 0.f, 0.f, 0.f};
#pragma unroll
    for (int f = 0; f < 14; ++f) {
        const int key = f * 16 + rl;
#pragma unroll
        for (int ks = 0; ks < 2; ++ks) {
            const int sl = (ks * 4 + kg) ^ (key & 7);
            sv8 kf = *reinterpret_cast<const sv8*>(&sKS[key * 64 + sl * 8]);
            sacc[f] = mfma16(qf[ks], kf, sacc[f]);
        }
    }

    float mx[4] = {-1e30f, -1e30f, -1e30f, -1e30f};
#pragma unroll
    for (int f = 0; f < 14; ++f) {
        const int col = f * 16 + rl;
#pragma unroll
        for (int r = 0; r < 4; ++r) {
            float s = sacc[f][r] * 0.125f;
            if (col >= 217) s = -1e30f;
            sacc[f][r] = s;
            mx[r] = fmaxf(mx[r], s);
        }
    }
#pragma unroll
    for (int o = 1; o < 16; o <<= 1)
#pragma unroll
        for (int r = 0; r < 4; ++r) mx[r] = fmaxf(mx[r], __shfl_xor(mx[r], o));
    float sm[4] = {0.f, 0.f, 0.f, 0.f};
#pragma unroll
    for (int f = 0; f < 14; ++f)
#pragma unroll
        for (int r = 0; r < 4; ++r) {
            float e = __expf(sacc[f][r] - mx[r]);
            sacc[f][r] = e;
            sm[r] += e;
        }
#pragma unroll
    for (int o = 1; o < 16; o <<= 1)
#pragma unroll
        for (int r = 0; r < 4; ++r) sm[r] += __shfl_xor(sm[r], o);
    float inv[4];
#pragma unroll
    for (int r = 0; r < 4; ++r) inv[r] = 1.0f / sm[r];

    __syncthreads();
    unsigned short* Sl = sKS;  // S [4 waves][16 q][232]
#pragma unroll
    for (int f = 0; f < 14; ++f)
#pragma unroll
        for (int r = 0; r < 4; ++r)
            Sl[(wave * 16 + kg * 4 + r) * 232 + f * 16 + rl] = f2bf(sacc[f][r] * inv[r]);
    __syncthreads();

    f32x4 oacc[4];
#pragma unroll
    for (int fd = 0; fd < 4; ++fd) oacc[fd] = f32x4{0.f, 0.f, 0.f, 0.f};
#pragma unroll
    for (int ks = 0; ks < 7; ++ks) {
        sv8 pf = *reinterpret_cast<const sv8*>(&Sl[(wave * 16 + rl) * 232 + ks * 32 + kg * 8]);
#pragma unroll
        for (int fd = 0; fd < 4; ++fd) {
            sv8 vf = *reinterpret_cast<const sv8*>(&sV[(fd * 16 + rl) * 232 + ks * 32 + kg * 8]);
            oacc[fd] = mfma16(pf, vf, oacc[fd]);
        }
    }

#pragma unroll
    for (int fd = 0; fd < 4; ++fd)
#pragma unroll
        for (int r = 0; r < 4; ++r) {
            const int q = qt * 64 + wave * 16 + kg * 4 + r;
            if (q < 197)
                obuf[((size_t)b * 197 + q) * 768 + h * 64 + fd * 16 + rl] = f2bf(oacc[fd][r]);
        }
}

// ---------------- host ----------------

extern "C" void kernel_launch(void* const* d_in, const int* in_sizes, int n_in,
                              void* d_out, int out_size, void* d_ws, size_t ws_size,
                              hipStream_t stream) {
    const float* x      = (const float*)d_in[0];
    const float* prompt = (const float*)d_in[1];
    const float* ln1_w  = (const float*)d_in[2];
    const float* ln1_b  = (const float*)d_in[3];
    const float* qkv_w  = (const float*)d_in[4];
    const float* qkv_b  = (const float*)d_in[5];
    const float* proj_w = (const float*)d_in[6];
    const float* proj_b = (const float*)d_in[7];
    const float* ln2_w  = (const float*)d_in[8];
    const float* ln2_b  = (const float*)d_in[9];
    const float* fc1_w  = (const float*)d_in[10];
    const float* fc1_b  = (const float*)d_in[11];
    const float* fc2_w  = (const float*)d_in[12];
    const float* fc2_b  = (const float*)d_in[13];

    char* ws = (char*)d_ws;
    size_t off = 0;
    auto bump = [&](size_t bytes) {
        char* p = ws + off;
        off += (bytes + 255) & ~(size_t)255;
        return p;
    };
    unsigned short* qkvw  = (unsigned short*)bump(2304UL * 768 * 2);
    unsigned short* projw = (unsigned short*)bump(768UL * 768 * 2);
    unsigned short* fc1w  = (unsigned short*)bump(3072UL * 768 * 2);
    unsigned short* fc2w  = (unsigned short*)bump(768UL * 3072 * 2);
    unsigned short* h2    = (unsigned short*)bump(12608UL * 768 * 2);
    float* xmid           = (float*)bump(12608UL * 768 * 4);
    char* pool = ws + off;
    unsigned short* h1   = (unsigned short*)(pool);
    unsigned short* Qg   = (unsigned short*)(pool + 19365888UL);
    unsigned short* Kg   = (unsigned short*)(pool + 38731776UL);
    unsigned short* Vtg  = (unsigned short*)(pool + 60751872UL);
    unsigned short* obuf = (unsigned short*)(pool + 82771968UL);
    unsigned short* mbuf = (unsigned short*)(pool);  // aliases h1/Q/K/Vt (dead by fc1)

    // fused prep: all 4 weight cvts + prompt rearrange + LN1 (one launch)
    prep_kernel<<<23360, 256, 0, stream>>>(
        qkv_w, proj_w, fc1_w, fc2_w, qkvw, projw, fc1w, fc2w,
        prompt, Kg, Vtg, x, ln1_w, ln1_b, h1);

    // qkv: 256x128 tiles (r11 best): 50 x 18 blocks, 512 threads
    gemm_bf16<EPI_QKV, 4, 2><<<50 * 18, 512, 0, stream>>>(
        h1, qkvw, qkv_b, nullptr, nullptr, Qg, Kg, Vtg, 12608, 2304, 768, 18);

    attn_kernel<<<dim3(4, 12, 64), 256, 0, stream>>>(Qg, Kg, Vtg, obuf);

    // proj: 128^2 (r10/r11 best)
    gemm_bf16<EPI_RES, 2, 2><<<99 * 6, 256, 0, stream>>>(
        obuf, projw, proj_b, x, xmid, nullptr, nullptr, nullptr, 12608, 768, 768, 6);

    ln_kernel<<<12608, 256, 0, stream>>>(xmid, ln2_w, ln2_b, h2);

    // fc1: 256x128 tiles (r11 best): 50 x 24 blocks, 512 threads
    gemm_bf16<EPI_GELU, 4, 2><<<50 * 24, 512, 0, stream>>>(
        h2, fc1w, fc1_b, nullptr, mbuf, nullptr, nullptr, nullptr, 12608, 3072, 768, 24);

    // fc2: 128^2, K=3072
    gemm_bf16<EPI_RES, 2, 2><<<99 * 6, 256, 0, stream>>>(
        mbuf, fc2w, fc2_b, xmid, (float*)d_out, nullptr, nullptr, nullptr, 12608, 768, 3072, 6);
}

// Round 16
// 405.987 us; speedup vs baseline: 1.3226x; 1.0113x over previous
//
#include <hip/hip_runtime.h>
#include <hip/hip_bf16.h>

typedef __attribute__((ext_vector_type(4))) float f32x4;
typedef __attribute__((ext_vector_type(8))) __bf16 bfv8;
typedef __attribute__((ext_vector_type(8))) short sv8;
typedef __attribute__((ext_vector_type(4))) unsigned short usv4;

// ---------------- helpers ----------------

static __device__ __forceinline__ f32x4 mfma16(sv8 a, sv8 b, f32x4 c) {
    return __builtin_amdgcn_mfma_f32_16x16x32_bf16(
        __builtin_bit_cast(bfv8, a), __builtin_bit_cast(bfv8, b), c, 0, 0, 0);
}

static __device__ __forceinline__ unsigned short f2bf(float f) {
    union { float f; unsigned int u; } v; v.f = f;
    unsigned int u = v.u;
    return (unsigned short)((u + 0x7FFFu + ((u >> 16) & 1u)) >> 16);  // RNE
}

static __device__ __forceinline__ float bf2f(unsigned short u) {
    union { unsigned int i; float f; } v; v.i = ((unsigned int)u) << 16;
    return v.f;
}

// async global->LDS, 16B per lane (dest linear in lane order)
static __device__ __forceinline__ void gld16(void* lds, const void* g) {
    __builtin_amdgcn_global_load_lds(
        (const __attribute__((address_space(1))) unsigned int*)g,
        (__attribute__((address_space(3))) unsigned int*)lds, 16, 0, 0);
}

// ---------------- vectorized LayerNorm rows (fp32-in and bf16-in variants) ----------------

static __device__ __forceinline__ void ln_row(const float* __restrict__ xr,
                                              const float* __restrict__ w,
                                              const float* __restrict__ b,
                                              unsigned short* __restrict__ outr,
                                              int t) {
    __shared__ float red[8];
    float4 v = {0.f, 0.f, 0.f, 0.f};
    float s = 0.f, ss = 0.f;
    if (t < 192) {
        v = reinterpret_cast<const float4*>(xr)[t];
        s = v.x + v.y + v.z + v.w;
        ss = v.x * v.x + v.y * v.y + v.z * v.z + v.w * v.w;
    }
#pragma unroll
    for (int o = 32; o; o >>= 1) { s += __shfl_xor(s, o); ss += __shfl_xor(ss, o); }
    if ((t & 63) == 0) { red[t >> 6] = s; red[4 + (t >> 6)] = ss; }
    __syncthreads();
    const float S = red[0] + red[1] + red[2];
    const float SS = red[4] + red[5] + red[6];
    const float mu = S * (1.0f / 768.0f);
    const float var = SS * (1.0f / 768.0f) - mu * mu;
    const float rstd = rsqrtf(var + 1e-6f);
    if (t < 192) {
        float4 wv = reinterpret_cast<const float4*>(w)[t];
        float4 bv = reinterpret_cast<const float4*>(b)[t];
        usv4 o = { f2bf((v.x - mu) * rstd * wv.x + bv.x),
                   f2bf((v.y - mu) * rstd * wv.y + bv.y),
                   f2bf((v.z - mu) * rstd * wv.z + bv.z),
                   f2bf((v.w - mu) * rstd * wv.w + bv.w) };
        reinterpret_cast<usv4*>(outr)[t] = o;
    }
}

// bf16-input LN (xmid stored bf16): 192 lanes x ushort4
__global__ void ln_b_kernel(const unsigned short* __restrict__ x, const float* __restrict__ w,
                            const float* __restrict__ b, unsigned short* __restrict__ out) {
    __shared__ float red[8];
    const size_t row = blockIdx.x;
    const int t = threadIdx.x;
    const unsigned short* xr = x + row * 768;
    float4 v = {0.f, 0.f, 0.f, 0.f};
    float s = 0.f, ss = 0.f;
    if (t < 192) {
        usv4 u = reinterpret_cast<const usv4*>(xr)[t];
        v.x = bf2f(u[0]); v.y = bf2f(u[1]); v.z = bf2f(u[2]); v.w = bf2f(u[3]);
        s = v.x + v.y + v.z + v.w;
        ss = v.x * v.x + v.y * v.y + v.z * v.z + v.w * v.w;
    }
#pragma unroll
    for (int o = 32; o; o >>= 1) { s += __shfl_xor(s, o); ss += __shfl_xor(ss, o); }
    if ((t & 63) == 0) { red[t >> 6] = s; red[4 + (t >> 6)] = ss; }
    __syncthreads();
    const float S = red[0] + red[1] + red[2];
    const float SS = red[4] + red[5] + red[6];
    const float mu = S * (1.0f / 768.0f);
    const float var = SS * (1.0f / 768.0f) - mu * mu;
    const float rstd = rsqrtf(var + 1e-6f);
    if (t < 192) {
        float4 wv = reinterpret_cast<const float4*>(w)[t];
        float4 bv = reinterpret_cast<const float4*>(b)[t];
        usv4 o = { f2bf((v.x - mu) * rstd * wv.x + bv.x),
                   f2bf((v.y - mu) * rstd * wv.y + bv.y),
                   f2bf((v.z - mu) * rstd * wv.z + bv.z),
                   f2bf((v.w - mu) * rstd * wv.w + bv.w) };
        reinterpret_cast<usv4*>(out + row * 768)[t] = o;
    }
}

// ---------------- fused prep: 4x weight-cvt + prompt rearrange + LN1 ----------------

__global__ void prep_kernel(const float* __restrict__ qkv_w, const float* __restrict__ proj_w,
                            const float* __restrict__ fc1_w, const float* __restrict__ fc2_w,
                            unsigned short* __restrict__ qkvw, unsigned short* __restrict__ projw,
                            unsigned short* __restrict__ fc1w, unsigned short* __restrict__ fc2w,
                            const float* __restrict__ pr,
                            unsigned short* __restrict__ k_out, unsigned short* __restrict__ v_out,
                            const float* __restrict__ x, const float* __restrict__ ln1_w,
                            const float* __restrict__ ln1_b, unsigned short* __restrict__ h1) {
    const int blk = blockIdx.x;
    const int tid = threadIdx.x;
    if (blk < 6912) {
        const float* in;
        unsigned short* out;
        int i;
        if (blk < 1728)      { in = qkv_w; out = qkvw; i = blk * 256 + tid; }
        else if (blk < 2304) { in = proj_w; out = projw; i = (blk - 1728) * 256 + tid; }
        else if (blk < 4608) { in = fc1_w; out = fc1w; i = (blk - 2304) * 256 + tid; }
        else                 { in = fc2_w; out = fc2w; i = (blk - 4608) * 256 + tid; }
        float4 f = reinterpret_cast<const float4*>(in)[i];
        usv4 o = { f2bf(f.x), f2bf(f.y), f2bf(f.z), f2bf(f.w) };
        reinterpret_cast<usv4*>(out)[i] = o;
    } else if (blk < 10752) {
        const int i = (blk - 6912) * 256 + tid;   // over B*P*H*64 = 983040
        const int d = i & 63;
        const int t = i >> 6;
        const int h = t % 12;
        const int t2 = t / 12;
        const int p = t2 % 20;
        const int b = t2 / 20;
        size_t src = ((((size_t)b * 20 + p) * 2 + 0) * 12 + h) * 64 + d;
        float kv = pr[src];
        float vv = pr[src + 12 * 64];  // s=1 plane
        k_out[(((size_t)(b * 12 + h) * 224 + p) << 6) + d] = f2bf(kv);
        v_out[((size_t)(b * 12 + h) * 64 + d) * 224 + p] = f2bf(vv);
    } else {
        const size_t row = blk - 10752;
        ln_row(x + row * 768, ln1_w, ln1_b, h1 + row * 768, tid);
    }
}

#define EPI_QKV 0
#define EPI_XMID 1
#define EPI_GELU 2
#define EPI_FINAL 3

// ---------------- epilogue ----------------

template <int EPI>
static __device__ __forceinline__ void gemm_epilogue(
        f32x4 (&acc)[4][4], int bmBase, int bnBase, int wm, int wn,
        int rl, int kg, const float* bias, const void* resid, void* out0,
        unsigned short* q_out, unsigned short* k_out, unsigned short* v_out,
        int M, int N) {
#pragma unroll
    for (int i = 0; i < 4; ++i) {
        const int m0 = bmBase + wm * 64 + i * 16 + kg * 4;
#pragma unroll
        for (int j = 0; j < 4; ++j) {
            const int ncol = bnBase + wn * 64 + j * 16 + rl;
            const float bia = bias[ncol];
#pragma unroll
            for (int r = 0; r < 4; ++r) {
                const int m = m0 + r;
                if (m >= M) continue;
                float vv = acc[i][j][r] + bia;
                const size_t idx = (size_t)m * N + ncol;
                if constexpr (EPI == EPI_QKV) {
                    int b = m / 197, nn = m - b * 197;
                    int which = ncol / 768;
                    int rc = ncol - which * 768;
                    int h = rc >> 6;
                    int d = ncol & 63;
                    if (which == 0)
                        q_out[(((size_t)(b * 12 + h) * 197 + nn) << 6) + d] = f2bf(vv);
                    else if (which == 1)
                        k_out[(((size_t)(b * 12 + h) * 224 + 20 + nn) << 6) + d] = f2bf(vv);
                    else
                        v_out[((size_t)(b * 12 + h) * 64 + d) * 224 + 20 + nn] = f2bf(vv);
                } else if constexpr (EPI == EPI_XMID) {
                    // proj: xmid (bf16) = attn_out@W^T + b + x (f32)
                    ((unsigned short*)out0)[idx] = f2bf(vv + ((const float*)resid)[idx]);
                } else if constexpr (EPI == EPI_FINAL) {
                    // fc2: d_out (f32) = m@W^T + b + xmid (bf16)
                    ((float*)out0)[idx] = vv + bf2f(((const unsigned short*)resid)[idx]);
                } else {  // GELU tanh-approx in sigmoid form
                    float g = vv / (1.0f + __expf(-1.5957691216f * vv * (1.0f + 0.044715f * vv * vv)));
                    ((unsigned short*)out0)[idx] = f2bf(g);
                }
            }
        }
    }
}

// ---------------- r11-best synced GEMM: tile (WM*64) x (WN*64), per-wave 64x64 ----------------
// 2-buffer LDS, stage(t+1) at iter start, one __syncthreads per iter. Linear staging.
// Plateau (r5-r15): ~430-480 TF for this shape class (K=768/3072, N<=3072), invariant
// under occupancy/BK/depth/swizzle/L2-tiling/tile-aspect/barrier-removal; at/above the
// guide's m102 curve for sub-4k shapes. 8-phase deep pipeline falsified here (r3);
// fp8 numerically barred by the 0.114 absmax threshold (~2.6% rms e4m3 rounding).

template <int EPI, int WM, int WN>
__global__ void __launch_bounds__(WM * WN * 64)
gemm_bf16(const unsigned short* __restrict__ A,
          const unsigned short* __restrict__ W,
          const float* __restrict__ bias,
          const void* __restrict__ resid,
          void* __restrict__ out0,
          unsigned short* __restrict__ q_out,
          unsigned short* __restrict__ k_out,
          unsigned short* __restrict__ v_out,
          int M, int N, int K, int NB) {
    constexpr int THREADS = WM * WN * 64;
    constexpr int BM = WM * 64, BN = WN * 64;
    constexpr int NCA = (BM * 4) / THREADS;
    constexpr int NCB = (BN * 4) / THREADS;
    __shared__ __align__(16) unsigned short As[2][BM * 32];
    __shared__ __align__(16) unsigned short Bs[2][BN * 32];
    const int tid = threadIdx.x;
    const int lane = tid & 63;
    const int wv = tid >> 6;
    const int wm = wv / WN, wn = wv % WN;
    const int rl = lane & 15, kg = lane >> 4;

    // bijective XCD swizzle (m204); wg increases bn-fastest (bm = wg/NB)
    const int nwg = gridDim.x;
    const int orig = blockIdx.x;
    const int xcd = orig & 7;
    const int qq = nwg >> 3, rr = nwg & 7;
    const int wg = (xcd < rr ? xcd * (qq + 1) : rr * (qq + 1) + (xcd - rr) * qq) + (orig >> 3);
    const int bm = wg / NB, bn = wg - bm * NB;

    const unsigned short* pA[NCA];
    const unsigned short* pB[NCB];
#pragma unroll
    for (int i = 0; i < NCA; ++i) {
        const int c = i * THREADS + tid;
        const int row = c >> 2, sl = c & 3;
        int ar = bm * BM + row; ar = ar < M ? ar : M - 1;
        pA[i] = A + (size_t)ar * K + sl * 8;
    }
#pragma unroll
    for (int i = 0; i < NCB; ++i) {
        const int c = i * THREADS + tid;
        const int row = c >> 2, sl = c & 3;
        pB[i] = W + (size_t)(bn * BN + row) * K + sl * 8;
    }
    auto stage = [&](int sb, int kt) {
        const int k0 = kt << 5;
#pragma unroll
        for (int i = 0; i < NCA; ++i)
            gld16(&As[sb][(i * THREADS + tid) * 8], pA[i] + k0);
#pragma unroll
        for (int i = 0; i < NCB; ++i)
            gld16(&Bs[sb][(i * THREADS + tid) * 8], pB[i] + k0);
    };

    f32x4 acc[4][4];
#pragma unroll
    for (int i = 0; i < 4; ++i)
#pragma unroll
        for (int j = 0; j < 4; ++j) acc[i][j] = f32x4{0.f, 0.f, 0.f, 0.f};

    const int nk = K >> 5;
    stage(0, 0);
    __syncthreads();
    for (int kt = 0; kt < nk; ++kt) {
        const int cur = kt & 1;
        if (kt + 1 < nk) stage(cur ^ 1, kt + 1);   // issue next-tile loads EARLY
        sv8 af[4], bfr[4];
#pragma unroll
        for (int f = 0; f < 4; ++f) {
            const int ra = wm * 64 + f * 16 + rl;
            af[f] = *reinterpret_cast<const sv8*>(&As[cur][ra * 32 + kg * 8]);
            const int rb = wn * 64 + f * 16 + rl;
            bfr[f] = *reinterpret_cast<const sv8*>(&Bs[cur][rb * 32 + kg * 8]);
        }
#pragma unroll
        for (int i = 0; i < 4; ++i)
#pragma unroll
            for (int j = 0; j < 4; ++j) acc[i][j] = mfma16(af[i], bfr[j], acc[i][j]);
        __syncthreads();   // drains vmcnt (next buf staged) + lgkm; one barrier/iter
    }
    gemm_epilogue<EPI>(acc, bm * BM, bn * BN, wm, wn, rl, kg, bias, resid,
                       out0, q_out, k_out, v_out, M, N);
}

// ---------------- attention: per (b,h,qtile64): S=QK^T, softmax, O=PV ----------------

__global__ void attn_kernel(const unsigned short* __restrict__ Qg,
                            const unsigned short* __restrict__ Kg,
                            const unsigned short* __restrict__ Vtg,
                            unsigned short* __restrict__ obuf) {
    __shared__ __align__(16) unsigned short sKS[14848];  // max(224*64, 4*16*232)
    __shared__ __align__(16) unsigned short sV[64 * 232];
    const int tid = threadIdx.x;
    const int lane = tid & 63;
    const int wave = tid >> 6;
    const int rl = lane & 15, kg = lane >> 4;
    const int qt = blockIdx.x, h = blockIdx.y, b = blockIdx.z;
    const size_t bh = (size_t)b * 12 + h;
    const size_t qbase = bh * 197 * 64;
    const size_t kbase = bh * 224 * 64;
    const size_t vbase = bh * 64 * 224;

    int qrow = qt * 64 + wave * 16 + rl;
    if (qrow > 196) qrow = 196;
    sv8 qf[2];
#pragma unroll
    for (int ks = 0; ks < 2; ++ks)
        qf[ks] = *reinterpret_cast<const sv8*>(&Qg[qbase + (size_t)qrow * 64 + ks * 32 + kg * 8]);

#pragma unroll
    for (int i = 0; i < 7; ++i) {
        const int c = i * 256 + tid;       // 1792 chunks of 16B
        const int key = c >> 3, sl = c & 7;
        const int ssl = sl ^ (key & 7);
        gld16(&sKS[c * 8], &Kg[kbase + key * 64 + ssl * 8]);
    }
#pragma unroll
    for (int i = 0; i < 7; ++i) {
        const int c = i * 256 + tid;
        const int d = c / 28, sl = c - d * 28;
        sv8 val = *reinterpret_cast<const sv8*>(&Vtg[vbase + d * 224 + sl * 8]);
        *reinterpret_cast<sv8*>(&sV[d * 232 + sl * 8]) = val;
    }
    __syncthreads();

    f32x4 sacc[14];
#pragma unroll
    for (int f = 0; f < 14; ++f) sacc[f] = f32x4{0.f, 0.f, 0.f, 0.f};
#pragma unroll
    for (int f = 0; f < 14; ++f) {
        const int key = f * 16 + rl;
#pragma unroll
        for (int ks = 0; ks < 2; ++ks) {
            const int sl = (ks * 4 + kg) ^ (key & 7);
            sv8 kf = *reinterpret_cast<const sv8*>(&sKS[key * 64 + sl * 8]);
            sacc[f] = mfma16(qf[ks], kf, sacc[f]);
        }
    }

    float mx[4] = {-1e30f, -1e30f, -1e30f, -1e30f};
#pragma unroll
    for (int f = 0; f < 14; ++f) {
        const int col = f * 16 + rl;
#pragma unroll
        for (int r = 0; r < 4; ++r) {
            float s = sacc[f][r] * 0.125f;
            if (col >= 217) s = -1e30f;
            sacc[f][r] = s;
            mx[r] = fmaxf(mx[r], s);
        }
    }
#pragma unroll
    for (int o = 1; o < 16; o <<= 1)
#pragma unroll
        for (int r = 0; r < 4; ++r) mx[r] = fmaxf(mx[r], __shfl_xor(mx[r], o));
    float sm[4] = {0.f, 0.f, 0.f, 0.f};
#pragma unroll
    for (int f = 0; f < 14; ++f)
#pragma unroll
        for (int r = 0; r < 4; ++r) {
            float e = __expf(sacc[f][r] - mx[r]);
            sacc[f][r] = e;
            sm[r] += e;
        }
#pragma unroll
    for (int o = 1; o < 16; o <<= 1)
#pragma unroll
        for (int r = 0; r < 4; ++r) sm[r] += __shfl_xor(sm[r], o);
    float inv[4];
#pragma unroll
    for (int r = 0; r < 4; ++r) inv[r] = 1.0f / sm[r];

    __syncthreads();
    unsigned short* Sl = sKS;  // S [4 waves][16 q][232]
#pragma unroll
    for (int f = 0; f < 14; ++f)
#pragma unroll
        for (int r = 0; r < 4; ++r)
            Sl[(wave * 16 + kg * 4 + r) * 232 + f * 16 + rl] = f2bf(sacc[f][r] * inv[r]);
    __syncthreads();

    f32x4 oacc[4];
#pragma unroll
    for (int fd = 0; fd < 4; ++fd) oacc[fd] = f32x4{0.f, 0.f, 0.f, 0.f};
#pragma unroll
    for (int ks = 0; ks < 7; ++ks) {
        sv8 pf = *reinterpret_cast<const sv8*>(&Sl[(wave * 16 + rl) * 232 + ks * 32 + kg * 8]);
#pragma unroll
        for (int fd = 0; fd < 4; ++fd) {
            sv8 vf = *reinterpret_cast<const sv8*>(&sV[(fd * 16 + rl) * 232 + ks * 32 + kg * 8]);
            oacc[fd] = mfma16(pf, vf, oacc[fd]);
        }
    }

#pragma unroll
    for (int fd = 0; fd < 4; ++fd)
#pragma unroll
        for (int r = 0; r < 4; ++r) {
            const int q = qt * 64 + wave * 16 + kg * 4 + r;
            if (q < 197)
                obuf[((size_t)b * 197 + q) * 768 + h * 64 + fd * 16 + rl] = f2bf(oacc[fd][r]);
        }
}

// ---------------- host ----------------

extern "C" void kernel_launch(void* const* d_in, const int* in_sizes, int n_in,
                              void* d_out, int out_size, void* d_ws, size_t ws_size,
                              hipStream_t stream) {
    const float* x      = (const float*)d_in[0];
    const float* prompt = (const float*)d_in[1];
    const float* ln1_w  = (const float*)d_in[2];
    const float* ln1_b  = (const float*)d_in[3];
    const float* qkv_w  = (const float*)d_in[4];
    const float* qkv_b  = (const float*)d_in[5];
    const float* proj_w = (const float*)d_in[6];
    const float* proj_b = (const float*)d_in[7];
    const float* ln2_w  = (const float*)d_in[8];
    const float* ln2_b  = (const float*)d_in[9];
    const float* fc1_w  = (const float*)d_in[10];
    const float* fc1_b  = (const float*)d_in[11];
    const float* fc2_w  = (const float*)d_in[12];
    const float* fc2_b  = (const float*)d_in[13];

    char* ws = (char*)d_ws;
    size_t off = 0;
    auto bump = [&](size_t bytes) {
        char* p = ws + off;
        off += (bytes + 255) & ~(size_t)255;
        return p;
    };
    unsigned short* qkvw  = (unsigned short*)bump(2304UL * 768 * 2);
    unsigned short* projw = (unsigned short*)bump(768UL * 768 * 2);
    unsigned short* fc1w  = (unsigned short*)bump(3072UL * 768 * 2);
    unsigned short* fc2w  = (unsigned short*)bump(768UL * 3072 * 2);
    unsigned short* h2    = (unsigned short*)bump(12608UL * 768 * 2);
    unsigned short* xmid  = (unsigned short*)bump(12608UL * 768 * 2);  // bf16 now
    char* pool = ws + off;
    unsigned short* h1   = (unsigned short*)(pool);
    unsigned short* Qg   = (unsigned short*)(pool + 19365888UL);
    unsigned short* Kg   = (unsigned short*)(pool + 38731776UL);
    unsigned short* Vtg  = (unsigned short*)(pool + 60751872UL);
    unsigned short* obuf = (unsigned short*)(pool + 82771968UL);
    unsigned short* mbuf = (unsigned short*)(pool);  // aliases h1/Q/K/Vt (dead by fc1)

    // fused prep: all 4 weight cvts + prompt rearrange + LN1 (one launch)
    prep_kernel<<<23360, 256, 0, stream>>>(
        qkv_w, proj_w, fc1_w, fc2_w, qkvw, projw, fc1w, fc2w,
        prompt, Kg, Vtg, x, ln1_w, ln1_b, h1);

    // qkv: 256x128 tiles (r11 best): 50 x 18 blocks, 512 threads
    gemm_bf16<EPI_QKV, 4, 2><<<50 * 18, 512, 0, stream>>>(
        h1, qkvw, qkv_b, nullptr, nullptr, Qg, Kg, Vtg, 12608, 2304, 768, 18);

    attn_kernel<<<dim3(4, 12, 64), 256, 0, stream>>>(Qg, Kg, Vtg, obuf);

    // proj: 128^2; writes bf16 xmid (+x residual fp32)
    gemm_bf16<EPI_XMID, 2, 2><<<99 * 6, 256, 0, stream>>>(
        obuf, projw, proj_b, x, xmid, nullptr, nullptr, nullptr, 12608, 768, 768, 6);

    // LN2 on bf16 xmid
    ln_b_kernel<<<12608, 256, 0, stream>>>(xmid, ln2_w, ln2_b, h2);

    // fc1: 256x128 tiles: 50 x 24 blocks, 512 threads (GELU -> bf16 mbuf)
    gemm_bf16<EPI_GELU, 4, 2><<<50 * 24, 512, 0, stream>>>(
        h2, fc1w, fc1_b, nullptr, mbuf, nullptr, nullptr, nullptr, 12608, 3072, 768, 24);

    // fc2: 128^2, K=3072; reads bf16 xmid residual, writes fp32 d_out
    gemm_bf16<EPI_FINAL, 2, 2><<<99 * 6, 256, 0, stream>>>(
        mbuf, fc2w, fc2_b, xmid, (float*)d_out, nullptr, nullptr, nullptr, 12608, 768, 3072, 6);
}